// Round 16
// baseline (269.008 us; speedup 1.0000x reference)
//
#include <hip/hip_runtime.h>

#define NHEADS 16
#define HD 128
#define LSEQ 2048
#define NBATCH 2
#define HDIM 2048
#define NQKV 6144
#define SCALE 0.08838834764831845f

typedef __attribute__((ext_vector_type(8))) short bfx8;
typedef __attribute__((ext_vector_type(4))) short bfx4;
typedef __attribute__((ext_vector_type(4))) float f32x4;

__device__ __forceinline__ unsigned short f2bf(float x) {
  unsigned u = __float_as_uint(x);
  u += 0x7fffu + ((u >> 16) & 1u);
  return (unsigned short)(u >> 16);
}
__device__ __forceinline__ float bf2f(unsigned short u) {
  return __uint_as_float(((unsigned)u) << 16);
}
__device__ __forceinline__ void gload_lds16(const void* g, void* l) {
  __builtin_amdgcn_global_load_lds(
      (const __attribute__((address_space(1))) unsigned int*)g,
      (__attribute__((address_space(3))) unsigned int*)l, 16, 0, 0);
}

// ---------------- fused cast f32 -> bf16 (x plain; w_qkv row-permuted; w_o col-permuted) ----------------
// RoPE-pair permutation: dd in [0,128) -> pos = ((d2>>3)<<4)|(d2&7)|(hi<<3), d2=dd&63, hi=dd>>6.
// Pairs (d2, d2+64) land at positions (p, p^8) => partner is the adjacent 8-col block.
__global__ __launch_bounds__(256) void cast_all_kernel(
    const float* __restrict__ x, const float* __restrict__ wq,
    const float* __restrict__ wo, unsigned short* __restrict__ xb,
    unsigned short* __restrict__ wqb, unsigned short* __restrict__ wob) {
  int i = blockIdx.x * 256 + threadIdx.x;
  const float* in;
  unsigned short* out;
  int li, lo;
  if (i < 2097152) {
    in = x; out = xb; li = i; lo = i;
  } else if (i < 2097152 + 3145728) {
    in = wq; out = wqb; li = i - 2097152;
    int r = li >> 9, c4 = li & 511;
    int seg = r >> 11, within = r & 2047;
    int h = within >> 7, dd = within & 127;
    int d2 = dd & 63, hi = dd >> 6;
    int pos = ((d2 >> 3) << 4) | (d2 & 7) | (hi << 3);
    lo = (((seg << 11) + (h << 7) + pos) << 9) + c4;
  } else {
    in = wo; out = wob; li = i - (2097152 + 3145728);
    int n = li >> 9, c4 = li & 511;
    int k0 = c4 << 2;
    int h = k0 >> 7, dd = k0 & 127;
    int d2 = dd & 63, hi = dd >> 6;
    int pos = ((d2 >> 3) << 4) | (d2 & 7) | (hi << 3);
    lo = (n << 9) + (h << 5) + (pos >> 2);
  }
  float4 v = ((const float4*)in)[li];
  bfx4 o;
  o[0] = (short)f2bf(v.x);
  o[1] = (short)f2bf(v.y);
  o[2] = (short)f2bf(v.z);
  o[3] = (short)f2bf(v.w);
  ((bfx4*)out)[lo] = o;
}

// ---------------- RoPE cos/sin table: tbl[l][d2] = {cos, sin} ----------------
__global__ __launch_bounds__(256) void table_kernel(float2* __restrict__ tbl) {
  int idx = blockIdx.x * 256 + threadIdx.x;  // 2048*64
  int l = idx >> 6, d2 = idx & 63;
  float invf = exp2f(-(float)d2 * 0.2076205059304601f);
  float s, c;
  sincosf((float)l * invf, &s, &c);
  tbl[idx] = (float2){c, s};
}

// ---------------- QKV GEMM 128x192 + fused RoPE/scatter epilogue (LDS-routed) ----------------
__global__ __launch_bounds__(512, 4) void gemm_qkv_kernel(
    const unsigned short* __restrict__ A, const unsigned short* __restrict__ B,
    unsigned short* __restrict__ Qo, unsigned short* __restrict__ Ko,
    unsigned short* __restrict__ Vt, const float2* __restrict__ tbl) {
  constexpr int K = 2048, BN = 192, NF = 3;
  constexpr int BNP = 200;  // padded row stride for epilogue [128][200] (16B-aligned rows)
  __shared__ unsigned short smem[(128 + BN) * 64 * 2];  // 80 KB staging; reused by epilogue (51 KB)
  unsigned short* lA0 = smem;
  unsigned short* lB0 = smem + 2 * 128 * 64;
  const int tid = threadIdx.x;
  const int w = tid >> 6, lane = tid & 63;
  const int g = lane >> 4, ln = lane & 15;
  const int nnt = 32;
  const int nwg = 32 * 32;
  const int bid = blockIdx.x;
  const int swz = (bid & 7) * (nwg >> 3) + (bid >> 3);
  const int bm = (swz / nnt) * 128, bn = (swz % nnt) * BN;
  const int wm = (w >> 2) * 64;
  const int wn = (w & 3) * 48;
  const unsigned short* At = A + (size_t)bm * K;
  const unsigned short* Bt = B + (size_t)bn * K;

  auto STG = [&](const unsigned short* src, unsigned short* dst, int q, int k0) {
    int rid = q * 64 + w * 8 + (lane >> 3);
    int slot = lane & 7;
    gload_lds16(src + (size_t)rid * K + k0 + ((slot ^ (rid & 7)) << 3),
                dst + (size_t)(q * 4096 + w * 512));
  };
  auto STAGE_ALL = [&](int buf, int k0) {
#pragma unroll
    for (int q = 0; q < 3; ++q) STG(Bt, lB0 + buf * (BN * 64), q, k0);
#pragma unroll
    for (int q = 0; q < 2; ++q) STG(At, lA0 + buf * (128 * 64), q, k0);
  };

  f32x4 acc[4][NF];
#pragma unroll
  for (int i = 0; i < 4; ++i)
#pragma unroll
    for (int j = 0; j < NF; ++j) acc[i][j] = (f32x4){0.f, 0.f, 0.f, 0.f};

  STAGE_ALL(0, 0);
  asm volatile("s_waitcnt vmcnt(0)" ::: "memory");
  __builtin_amdgcn_s_barrier();

  const int nt = K >> 6;
  for (int t = 0; t < nt; ++t) {
    const int cur = t & 1;
    const char* lAc = (const char*)(lA0 + cur * (128 * 64));
    const char* lBc = (const char*)(lB0 + cur * (BN * 64));
    const bool more = (t + 1 < nt);
    if (more) STAGE_ALL(cur ^ 1, (t + 1) << 6);

    bfx8 bfrag[NF][2];
#pragma unroll
    for (int nf = 0; nf < NF; ++nf)
#pragma unroll
      for (int kk = 0; kk < 2; ++kk)
        bfrag[nf][kk] = *(const bfx8*)(lBc + (wn + nf * 16 + ln) * 128 +
                                       (((kk * 4 + g) ^ (ln & 7)) << 4));
#pragma unroll
    for (int mf = 0; mf < 4; ++mf) {
      bfx8 afrag[2];
#pragma unroll
      for (int kk = 0; kk < 2; ++kk)
        afrag[kk] = *(const bfx8*)(lAc + (wm + mf * 16 + ln) * 128 +
                                   (((kk * 4 + g) ^ (ln & 7)) << 4));
#pragma unroll
      for (int kk = 0; kk < 2; ++kk)
#pragma unroll
        for (int nf = 0; nf < NF; ++nf)
          acc[mf][nf] = __builtin_amdgcn_mfma_f32_16x16x32_bf16(
              afrag[kk], bfrag[nf][kk], acc[mf][nf], 0, 0, 0);
    }

    asm volatile("s_waitcnt vmcnt(0)" ::: "memory");
    __builtin_amdgcn_s_barrier();
  }

  // ---- fused epilogue, phase 1: all fragments -> smem[row][c] (bf16) ----
#pragma unroll
  for (int nf = 0; nf < NF; ++nf) {
    int c = wn + nf * 16 + ln;
#pragma unroll
    for (int mf = 0; mf < 4; ++mf)
#pragma unroll
      for (int r = 0; r < 4; ++r)
        smem[(wm + mf * 16 + g * 4 + r) * BNP + c] = f2bf(acc[mf][nf][r]);
  }
  __syncthreads();

  // ---- phase 2a: Q/K blocks -> RoPE rotate -> coalesced bfx8 stores ----
  const int bb = bm >> 11, l0 = bm & 2047;
#pragma unroll
  for (int it = 0; it < 6; ++it) {
    int idx = it * 512 + tid;            // 3072 = 128 rows * 24 col-blocks
    int blk = idx % 24, row = idx / 24;
    int gcol0 = bn + blk * 8;
    int seg = gcol0 >> 11;
    if (seg < 2) {
      int h = (gcol0 & 2047) >> 7;
      int pdd0 = gcol0 & 127;
      int d20 = ((pdd0 >> 4) << 3) | (pdd0 & 7);
      float sgn = (pdd0 & 8) ? 1.f : -1.f;
      int c0 = blk * 8;
      bfx8 v = *(const bfx8*)(smem + row * BNP + c0);
      bfx8 p = *(const bfx8*)(smem + row * BNP + (c0 ^ 8));
      const float2* tp = tbl + (((l0 + row) << 6) + d20);
      bfx8 o;
#pragma unroll
      for (int e = 0; e < 8; ++e) {
        float2 cs = tp[e];
        o[e] = (short)f2bf(bf2f((unsigned short)v[e]) * cs.x +
                           sgn * bf2f((unsigned short)p[e]) * cs.y);
      }
      unsigned short* dst = (seg == 0) ? Qo : Ko;
      *(bfx8*)(dst + (((size_t)((bb << 4) + h) * 2048 + l0 + row) << 7) + pdd0) = o;
    }
  }
  // ---- phase 2b: V columns -> transposed bfx8 stores to Vt ----
  if (bn + BN > 4096) {
    int cs0 = (bn < 4096) ? (4096 - bn) : 0;
    int nV = BN - cs0;
    for (int idx = tid; idx < nV * 16; idx += 512) {
      int c = cs0 + (idx >> 4), part = idx & 15;
      int gcol = bn + c;
      int h = (gcol & 2047) >> 7, pdd = gcol & 127;
      bfx8 vv;
#pragma unroll
      for (int rr = 0; rr < 8; ++rr)
        vv[rr] = (short)smem[(part * 8 + rr) * BNP + c];
      *(bfx8*)(Vt + (((size_t)((bb << 4) + h) << 7) + pdd) * 2048 + l0 + part * 8) = vv;
    }
  }
}

// ---------------- GEMM 128 x BN, BK=64, 4 waves (2Mx2N), barrier-light (out-proj) ----------------
template<int NF, bool BF16OUT>
__global__ __launch_bounds__(256, 2) void gemm4w_kernel(
    const unsigned short* __restrict__ A, const unsigned short* __restrict__ B,
    void* __restrict__ Cout, int M, int N, int K) {
  constexpr int BN = 2 * NF * 16;
  constexpr int BQ = BN / 32;
  __shared__ unsigned short lA[2][128 * 64];
  __shared__ unsigned short lB[2][BN * 64];
  const int tid = threadIdx.x;
  const int w = tid >> 6, lane = tid & 63;
  const int g = lane >> 4, ln = lane & 15;
  const int nmt = M >> 7, nnt = N / BN;
  const int nwg = nmt * nnt;
  const int bid = blockIdx.x;
  const int swz = (bid & 7) * (nwg >> 3) + (bid >> 3);
  const int bm = (swz / nnt) * 128, bn = (swz % nnt) * BN;
  const int wm = (w >> 1) * 64;
  const int wn = (w & 1) * (NF * 16);
  const unsigned short* At = A + (size_t)bm * K;
  const unsigned short* Bt = B + (size_t)bn * K;

  auto STG = [&](const unsigned short* src, unsigned short* dst, int q, int k0) {
    int rid = q * 32 + w * 8 + (lane >> 3);
    int slot = lane & 7;
    gload_lds16(src + (size_t)rid * K + k0 + ((slot ^ (rid & 7)) << 3),
                dst + (size_t)(q * 2048 + w * 512));
  };
  auto STAGE_ALL = [&](int buf, int k0) {
#pragma unroll
    for (int q = 0; q < BQ; ++q) STG(Bt, lB[buf], q, k0);
#pragma unroll
    for (int q = 0; q < 4; ++q) STG(At, lA[buf], q, k0);
  };

  f32x4 acc[4][NF];
#pragma unroll
  for (int i = 0; i < 4; ++i)
#pragma unroll
    for (int j = 0; j < NF; ++j) acc[i][j] = (f32x4){0.f, 0.f, 0.f, 0.f};

  STAGE_ALL(0, 0);
  asm volatile("s_waitcnt vmcnt(0)" ::: "memory");
  __builtin_amdgcn_s_barrier();

  const int nt = K >> 6;
  for (int t = 0; t < nt; ++t) {
    const int cur = t & 1;
    const char* lAc = (const char*)lA[cur];
    const char* lBc = (const char*)lB[cur];
    const bool more = (t + 1 < nt);
    if (more) STAGE_ALL(cur ^ 1, (t + 1) << 6);

    bfx8 bfrag[NF][2];
#pragma unroll
    for (int nf = 0; nf < NF; ++nf)
#pragma unroll
      for (int kk = 0; kk < 2; ++kk)
        bfrag[nf][kk] = *(const bfx8*)(lBc + (wn + nf * 16 + ln) * 128 +
                                       (((kk * 4 + g) ^ (ln & 7)) << 4));
#pragma unroll
    for (int mf = 0; mf < 4; ++mf) {
      bfx8 afrag[2];
#pragma unroll
      for (int kk = 0; kk < 2; ++kk)
        afrag[kk] = *(const bfx8*)(lAc + (wm + mf * 16 + ln) * 128 +
                                   (((kk * 4 + g) ^ (ln & 7)) << 4));
#pragma unroll
      for (int kk = 0; kk < 2; ++kk)
#pragma unroll
        for (int nf = 0; nf < NF; ++nf)
          acc[mf][nf] = __builtin_amdgcn_mfma_f32_16x16x32_bf16(
              afrag[kk], bfrag[nf][kk], acc[mf][nf], 0, 0, 0);
    }

    asm volatile("s_waitcnt vmcnt(0)" ::: "memory");
    __builtin_amdgcn_s_barrier();
  }

#pragma unroll
  for (int mf = 0; mf < 4; ++mf) {
    int row0 = bm + wm + mf * 16 + g * 4;
#pragma unroll
    for (int nf = 0; nf < NF; ++nf) {
      int col = bn + wn + nf * 16 + ln;
#pragma unroll
      for (int r = 0; r < 4; ++r) {
        if constexpr (BF16OUT)
          ((unsigned short*)Cout)[(size_t)(row0 + r) * N + col] = f2bf(acc[mf][nf][r]);
        else
          ((float*)Cout)[(size_t)(row0 + r) * N + col] = acc[mf][nf][r];
      }
    }
  }
}

// ---------------- Flash attention: 8 waves, q-tile 128, KV chunk 64, LDS-staged ----------------
__global__ __launch_bounds__(512, 4) void flash_kernel(
    const unsigned short* __restrict__ Q, const unsigned short* __restrict__ K,
    const unsigned short* __restrict__ Vt, unsigned short* __restrict__ O) {
  __shared__ unsigned short lKs[2][64 * 128];
  __shared__ unsigned short lVs[2][128 * 64];
  __shared__ unsigned short lP[8][16 * 40];
  const int bh = blockIdx.x;
  const int qy = (int)blockIdx.y;
  const int qt = (qy < 8) ? (15 - qy) : (qy - 8);
  const int q0 = qt * 128;
  const int tid = threadIdx.x;
  const int w = tid >> 6, lane = tid & 63;
  const int g = lane >> 4, ln = lane & 15;
  const int q0w = q0 + w * 16;
  const unsigned short* Qb = Q + (size_t)bh * LSEQ * HD;
  const unsigned short* Kb = K + (size_t)bh * LSEQ * HD;
  const unsigned short* Vb = Vt + (size_t)bh * HD * LSEQ;
  unsigned short* Pw = lP[w];

  auto STAGE = [&](int buf, int kv0s) {
#pragma unroll
    for (int s = 0; s < 2; ++s) {
      int rl = s * 32 + w * 4 + (lane >> 4);
      int slot = lane & 15;
      const unsigned short* src =
          Kb + (size_t)(kv0s + rl) * HD + ((slot ^ (rl & 15)) * 8);
      gload_lds16(src, &lKs[buf][(s * 8192 + w * 1024) / 2]);
    }
#pragma unroll
    for (int s = 0; s < 2; ++s) {
      int d = s * 64 + w * 8 + (lane >> 3);
      int slot = lane & 7;
      const unsigned short* src =
          Vb + (size_t)d * LSEQ + kv0s + ((slot ^ (d & 7)) * 8);
      gload_lds16(src, &lVs[buf][(s * 8192 + w * 1024) / 2]);
    }
  };

  bfx8 qf[4];
#pragma unroll
  for (int c = 0; c < 4; ++c)
    qf[c] = *(const bfx8*)(Qb + (size_t)(q0w + ln) * HD + c * 32 + g * 8);

  f32x4 o[8];
#pragma unroll
  for (int dt = 0; dt < 8; ++dt) o[dt] = (f32x4){0.f, 0.f, 0.f, 0.f};
  float m = -1e30f, sum = 0.f;
  const int qg = q0w + ln;
  const int nch = 2 * qt + 2;

  STAGE(0, 0);
  __syncthreads();

  for (int ch = 0; ch < nch; ++ch) {
    const int kv0 = ch * 64;
    const int cur = ch & 1;
    if (ch + 1 < nch) STAGE(cur ^ 1, kv0 + 64);

    if (kv0 <= q0w + 15) {
      const char* lK0 = (const char*)lKs[cur];
      const char* lV0 = (const char*)lVs[cur];
      f32x4 s4[4];
#pragma unroll
      for (int kt = 0; kt < 4; ++kt) s4[kt] = (f32x4){0.f, 0.f, 0.f, 0.f};
      __builtin_amdgcn_s_setprio(1);
#pragma unroll
      for (int c = 0; c < 4; ++c) {
        const int cbb = c * 64 + g * 16;
#pragma unroll
        for (int kt = 0; kt < 4; ++kt) {
          bfx8 kf = *(const bfx8*)(lK0 + (kt * 16 + ln) * 256 + (cbb ^ (ln << 4)));
          s4[kt] = __builtin_amdgcn_mfma_f32_16x16x32_bf16(kf, qf[c], s4[kt], 0, 0, 0);
        }
      }
      __builtin_amdgcn_s_setprio(0);
      float tm = -1e30f;
      if (kv0 + 63 <= q0w) {
#pragma unroll
        for (int kt = 0; kt < 4; ++kt)
#pragma unroll
          for (int r = 0; r < 4; ++r) {
            s4[kt][r] *= SCALE;
            tm = fmaxf(tm, s4[kt][r]);
          }
      } else {
#pragma unroll
        for (int kt = 0; kt < 4; ++kt)
#pragma unroll
          for (int r = 0; r < 4; ++r) {
            int kvr = kv0 + kt * 16 + 4 * g + r;
            float v = (kvr <= qg) ? s4[kt][r] * SCALE : -1e30f;
            s4[kt][r] = v;
            tm = fmaxf(tm, v);
          }
      }
      tm = fmaxf(tm, __shfl_xor(tm, 16));
      tm = fmaxf(tm, __shfl_xor(tm, 32));
      float f = 1.f;
      const bool dorescale = !__all(tm <= m + 8.f);
      if (dorescale) {
        float mnew = fmaxf(m, tm);
        f = __expf(m - mnew);
        m = mnew;
      }
      float ts = 0.f;
      bfx4 pb4[4];
#pragma unroll
      for (int kt = 0; kt < 4; ++kt)
#pragma unroll
        for (int r = 0; r < 4; ++r) {
          float p = __expf(s4[kt][r] - m);
          ts += p;
          pb4[kt][r] = (short)f2bf(p);
        }
      ts += __shfl_xor(ts, 16);
      ts += __shfl_xor(ts, 32);
      sum = sum * f + ts;
      float fr0 = 1.f, fr1 = 1.f, fr2 = 1.f, fr3 = 1.f;
      if (dorescale) {
        fr0 = __shfl(f, 4 * g + 0);
        fr1 = __shfl(f, 4 * g + 1);
        fr2 = __shfl(f, 4 * g + 2);
        fr3 = __shfl(f, 4 * g + 3);
      }
#pragma unroll
      for (int kvh = 0; kvh < 2; ++kvh) {
        asm volatile("s_waitcnt lgkmcnt(0)" ::: "memory");
        __builtin_amdgcn_sched_barrier(0);
        *(bfx4*)(Pw + ln * 40 + 4 * g) = pb4[2 * kvh];
        *(bfx4*)(Pw + ln * 40 + 16 + 4 * g) = pb4[2 * kvh + 1];
        asm volatile("s_waitcnt lgkmcnt(0)" ::: "memory");
        __builtin_amdgcn_sched_barrier(0);
        bfx8 pf = *(const bfx8*)(Pw + ln * 40 + g * 8);
        if (kvh == 0 && dorescale) {
#pragma unroll
          for (int dt = 0; dt < 8; ++dt) {
            o[dt][0] *= fr0; o[dt][1] *= fr1; o[dt][2] *= fr2; o[dt][3] *= fr3;
          }
        }
        __builtin_amdgcn_s_setprio(1);
#pragma unroll
        for (int dt = 0; dt < 8; ++dt) {
          bfx8 vf = *(const bfx8*)(lV0 + (dt * 16 + ln) * 128 +
                                   ((kvh * 64 + g * 16) ^ ((ln & 7) << 4)));
          o[dt] = __builtin_amdgcn_mfma_f32_16x16x32_bf16(pf, vf, o[dt], 0, 0, 0);
        }
        __builtin_amdgcn_s_setprio(0);
      }
    }
    __syncthreads();
  }

  float inv = 1.f / sum;
  float ir0 = __shfl(inv, 4 * g + 0);
  float ir1 = __shfl(inv, 4 * g + 1);
  float ir2 = __shfl(inv, 4 * g + 2);
  float ir3 = __shfl(inv, 4 * g + 3);
  const int b = bh >> 4, h = bh & 15;
  unsigned short* Ob = O + (size_t)b * LSEQ * HDIM + h * HD;
#pragma unroll
  for (int dt = 0; dt < 8; ++dt) {
    Ob[(size_t)(q0w + 4 * g + 0) * HDIM + dt * 16 + ln] = f2bf(o[dt][0] * ir0);
    Ob[(size_t)(q0w + 4 * g + 1) * HDIM + dt * 16 + ln] = f2bf(o[dt][1] * ir1);
    Ob[(size_t)(q0w + 4 * g + 2) * HDIM + dt * 16 + ln] = f2bf(o[dt][2] * ir2);
    Ob[(size_t)(q0w + 4 * g + 3) * HDIM + dt * 16 + ln] = f2bf(o[dt][3] * ir3);
  }
}

// ---------------- launch ----------------
extern "C" void kernel_launch(void* const* d_in, const int* in_sizes, int n_in,
                              void* d_out, int out_size, void* d_ws, size_t ws_size,
                              hipStream_t stream) {
  const float* x = (const float*)d_in[0];
  const float* w_qkv = (const float*)d_in[1];
  const float* w_o = (const float*)d_in[2];
  float* out = (float*)d_out;
  char* ws = (char*)d_ws;

  unsigned short* xb    = (unsigned short*)(ws + 0);
  unsigned short* wqkvb = (unsigned short*)(ws + 16777216);
  unsigned short* wob   = (unsigned short*)(ws + 41943040);
  unsigned short* qb    = (unsigned short*)(ws + 100663296);
  unsigned short* kb    = (unsigned short*)(ws + 117440512);
  unsigned short* vtb   = (unsigned short*)(ws + 134217728);
  float2* tbl           = (float2*)(ws + 150994944);
  unsigned short* attnb = (unsigned short*)(ws + 0);

  cast_all_kernel<<<24576, 256, 0, stream>>>(x, w_qkv, w_o, xb, wqkvb, wob);
  table_kernel<<<512, 256, 0, stream>>>(tbl);

  gemm_qkv_kernel<<<1024, 512, 0, stream>>>(xb, wqkvb, qb, kb, vtb, tbl);

  flash_kernel<<<dim3(32, 16), 512, 0, stream>>>(qb, kb, vtb, attnb);

  gemm4w_kernel<4, false><<<(4096 / 128) * (2048 / 128), 256, 0, stream>>>(
      attnb, wob, (void*)out, 4096, 2048, 2048);
}

// Round 17
// 257.092 us; speedup vs baseline: 1.0464x; 1.0464x over previous
//
#include <hip/hip_runtime.h>

#define NHEADS 16
#define HD 128
#define LSEQ 2048
#define NBATCH 2
#define HDIM 2048
#define NQKV 6144
#define SCALE 0.08838834764831845f

typedef __attribute__((ext_vector_type(8))) short bfx8;
typedef __attribute__((ext_vector_type(4))) short bfx4;
typedef __attribute__((ext_vector_type(4))) float f32x4;

__device__ __forceinline__ unsigned short f2bf(float x) {
  unsigned u = __float_as_uint(x);
  u += 0x7fffu + ((u >> 16) & 1u);
  return (unsigned short)(u >> 16);
}
__device__ __forceinline__ float bf2f(unsigned short u) {
  return __uint_as_float(((unsigned)u) << 16);
}
__device__ __forceinline__ void gload_lds16(const void* g, void* l) {
  __builtin_amdgcn_global_load_lds(
      (const __attribute__((address_space(1))) unsigned int*)g,
      (__attribute__((address_space(3))) unsigned int*)l, 16, 0, 0);
}

// ---------------- fused cast f32 -> bf16 (x plain; w_qkv row-permuted; w_o col-permuted) ----------------
// RoPE-pair permutation: dd -> pos = ((d2>>3)<<4)|(d2&7)|(hi<<3); pair partner at pos^8.
__global__ __launch_bounds__(256) void cast_all_kernel(
    const float* __restrict__ x, const float* __restrict__ wq,
    const float* __restrict__ wo, unsigned short* __restrict__ xb,
    unsigned short* __restrict__ wqb, unsigned short* __restrict__ wob) {
  int i = blockIdx.x * 256 + threadIdx.x;
  const float* in;
  unsigned short* out;
  int li, lo;
  if (i < 2097152) {
    in = x; out = xb; li = i; lo = i;
  } else if (i < 2097152 + 3145728) {
    in = wq; out = wqb; li = i - 2097152;
    int r = li >> 9, c4 = li & 511;
    int seg = r >> 11, within = r & 2047;
    int h = within >> 7, dd = within & 127;
    int d2 = dd & 63, hi = dd >> 6;
    int pos = ((d2 >> 3) << 4) | (d2 & 7) | (hi << 3);
    lo = (((seg << 11) + (h << 7) + pos) << 9) + c4;
  } else {
    in = wo; out = wob; li = i - (2097152 + 3145728);
    int n = li >> 9, c4 = li & 511;
    int k0 = c4 << 2;
    int h = k0 >> 7, dd = k0 & 127;
    int d2 = dd & 63, hi = dd >> 6;
    int pos = ((d2 >> 3) << 4) | (d2 & 7) | (hi << 3);
    lo = (n << 9) + (h << 5) + (pos >> 2);
  }
  float4 v = ((const float4*)in)[li];
  bfx4 o;
  o[0] = (short)f2bf(v.x);
  o[1] = (short)f2bf(v.y);
  o[2] = (short)f2bf(v.z);
  o[3] = (short)f2bf(v.w);
  ((bfx4*)out)[lo] = o;
}

// ---------------- RoPE cos/sin table ----------------
__global__ __launch_bounds__(256) void table_kernel(float2* __restrict__ tbl) {
  int idx = blockIdx.x * 256 + threadIdx.x;  // 2048*64
  int l = idx >> 6, d2 = idx & 63;
  float invf = exp2f(-(float)d2 * 0.2076205059304601f);
  float s, c;
  sincosf((float)l * invf, &s, &c);
  tbl[idx] = (float2){c, s};
}

// ---------------- QKV GEMM (4-wave, 128x192) + fused RoPE/scatter epilogue ----------------
// Body = R13's gemm4w<6>. Epilogue: acc -> smem[128][212] (conflict-free: row
// stride 106 dwords, Δrow=4 => +8 banks) -> rotate pairs (c^8) with table ->
// coalesced bfx8 stores to Qo/Ko; V columns -> transposed bfx8 stores to Vt.
__global__ __launch_bounds__(256, 2) void gemm_qkv_kernel(
    const unsigned short* __restrict__ A, const unsigned short* __restrict__ B,
    unsigned short* __restrict__ Qo, unsigned short* __restrict__ Ko,
    unsigned short* __restrict__ Vt, const float2* __restrict__ tbl) {
  constexpr int K = 2048, BN = 192, NF = 6;
  constexpr int BNP = 212;
  __shared__ unsigned short smem[(128 + BN) * 64 * 2];  // 80 KB staging; epilogue reuses 53 KB
  unsigned short* lA0 = smem;
  unsigned short* lB0 = smem + 2 * 128 * 64;
  const int tid = threadIdx.x;
  const int w = tid >> 6, lane = tid & 63;
  const int g = lane >> 4, ln = lane & 15;
  const int nnt = 32;
  const int nwg = 32 * 32;
  const int bid = blockIdx.x;
  const int swz = (bid & 7) * (nwg >> 3) + (bid >> 3);
  const int bm = (swz / nnt) * 128, bn = (swz % nnt) * BN;
  const int wm = (w >> 1) * 64;
  const int wn = (w & 1) * 96;
  const unsigned short* At = A + (size_t)bm * K;
  const unsigned short* Bt = B + (size_t)bn * K;

  auto STG = [&](const unsigned short* src, unsigned short* dst, int q, int k0) {
    int rid = q * 32 + w * 8 + (lane >> 3);
    int slot = lane & 7;
    gload_lds16(src + (size_t)rid * K + k0 + ((slot ^ (rid & 7)) << 3),
                dst + (size_t)(q * 2048 + w * 512));
  };
  auto STAGE_ALL = [&](int buf, int k0) {
#pragma unroll
    for (int q = 0; q < 6; ++q) STG(Bt, lB0 + buf * (BN * 64), q, k0);
#pragma unroll
    for (int q = 0; q < 4; ++q) STG(At, lA0 + buf * (128 * 64), q, k0);
  };

  f32x4 acc[4][NF];
#pragma unroll
  for (int i = 0; i < 4; ++i)
#pragma unroll
    for (int j = 0; j < NF; ++j) acc[i][j] = (f32x4){0.f, 0.f, 0.f, 0.f};

  STAGE_ALL(0, 0);
  asm volatile("s_waitcnt vmcnt(0)" ::: "memory");
  __builtin_amdgcn_s_barrier();

  const int nt = K >> 6;
  for (int t = 0; t < nt; ++t) {
    const int cur = t & 1;
    const char* lAc = (const char*)(lA0 + cur * (128 * 64));
    const char* lBc = (const char*)(lB0 + cur * (BN * 64));
    const bool more = (t + 1 < nt);
    if (more) STAGE_ALL(cur ^ 1, (t + 1) << 6);

    bfx8 bfrag[NF][2];
#pragma unroll
    for (int nf = 0; nf < NF; ++nf)
#pragma unroll
      for (int kk = 0; kk < 2; ++kk)
        bfrag[nf][kk] = *(const bfx8*)(lBc + (wn + nf * 16 + ln) * 128 +
                                       (((kk * 4 + g) ^ (ln & 7)) << 4));
#pragma unroll
    for (int mf = 0; mf < 4; ++mf) {
      bfx8 afrag[2];
#pragma unroll
      for (int kk = 0; kk < 2; ++kk)
        afrag[kk] = *(const bfx8*)(lAc + (wm + mf * 16 + ln) * 128 +
                                   (((kk * 4 + g) ^ (ln & 7)) << 4));
#pragma unroll
      for (int kk = 0; kk < 2; ++kk)
#pragma unroll
        for (int nf = 0; nf < NF; ++nf)
          acc[mf][nf] = __builtin_amdgcn_mfma_f32_16x16x32_bf16(
              afrag[kk], bfrag[nf][kk], acc[mf][nf], 0, 0, 0);
    }

    asm volatile("s_waitcnt vmcnt(0)" ::: "memory");
    __builtin_amdgcn_s_barrier();
  }

  // ---- epilogue phase 1: fragments -> smem[row][c] ----
#pragma unroll
  for (int nf = 0; nf < NF; ++nf) {
    int c = wn + nf * 16 + ln;
#pragma unroll
    for (int mf = 0; mf < 4; ++mf)
#pragma unroll
      for (int r = 0; r < 4; ++r)
        smem[(wm + mf * 16 + g * 4 + r) * BNP + c] = f2bf(acc[mf][nf][r]);
  }
  __syncthreads();

  // ---- phase 2a: Q/K 8-col blocks: rotate with table, coalesced bfx8 stores ----
  const int bb = bm >> 11, l0 = bm & 2047;
#pragma unroll
  for (int it = 0; it < 12; ++it) {
    int idx = it * 256 + tid;            // 3072 = 128 rows * 24 col-blocks
    int blk = idx % 24, row = idx / 24;
    int gcol0 = bn + blk * 8;
    int seg = gcol0 >> 11;
    if (seg < 2) {
      int h = (gcol0 & 2047) >> 7;
      int pdd0 = gcol0 & 127;
      int d20 = ((pdd0 >> 4) << 3) | (pdd0 & 7);
      float sgn = (pdd0 & 8) ? 1.f : -1.f;
      int c0 = blk * 8;
      bfx8 v = *(const bfx8*)(smem + row * BNP + c0);
      bfx8 p = *(const bfx8*)(smem + row * BNP + (c0 ^ 8));
      const float2* tp = tbl + (((l0 + row) << 6) + d20);
      bfx8 o;
#pragma unroll
      for (int e = 0; e < 8; ++e) {
        float2 cs = tp[e];
        o[e] = (short)f2bf(bf2f((unsigned short)v[e]) * cs.x +
                           sgn * bf2f((unsigned short)p[e]) * cs.y);
      }
      unsigned short* dst = (seg == 0) ? Qo : Ko;
      *(bfx8*)(dst + (((size_t)((bb << 4) + h) * 2048 + l0 + row) << 7) + pdd0) = o;
    }
  }
  // ---- phase 2b: V columns -> transposed bfx8 stores to Vt ----
  if (bn + BN > 4096) {
    int cs0 = (bn < 4096) ? (4096 - bn) : 0;
    int nV = BN - cs0;
    for (int idx = tid; idx < nV * 16; idx += 256) {
      int c = cs0 + (idx >> 4), part = idx & 15;
      int gcol = bn + c;
      int h = (gcol & 2047) >> 7, pdd = gcol & 127;
      bfx8 vv;
#pragma unroll
      for (int rr = 0; rr < 8; ++rr)
        vv[rr] = (short)smem[(part * 8 + rr) * BNP + c];
      *(bfx8*)(Vt + (((size_t)((bb << 4) + h) << 7) + pdd) * 2048 + l0 + part * 8) = vv;
    }
  }
}

// ---------------- GEMM 128 x BN, BK=64, 4 waves (2Mx2N), barrier-light (out-proj) ----------------
template<int NF, bool BF16OUT>
__global__ __launch_bounds__(256, 2) void gemm4w_kernel(
    const unsigned short* __restrict__ A, const unsigned short* __restrict__ B,
    void* __restrict__ Cout, int M, int N, int K) {
  constexpr int BN = 2 * NF * 16;
  constexpr int BQ = BN / 32;
  __shared__ unsigned short lA[2][128 * 64];
  __shared__ unsigned short lB[2][BN * 64];
  const int tid = threadIdx.x;
  const int w = tid >> 6, lane = tid & 63;
  const int g = lane >> 4, ln = lane & 15;
  const int nmt = M >> 7, nnt = N / BN;
  const int nwg = nmt * nnt;
  const int bid = blockIdx.x;
  const int swz = (bid & 7) * (nwg >> 3) + (bid >> 3);
  const int bm = (swz / nnt) * 128, bn = (swz % nnt) * BN;
  const int wm = (w >> 1) * 64;
  const int wn = (w & 1) * (NF * 16);
  const unsigned short* At = A + (size_t)bm * K;
  const unsigned short* Bt = B + (size_t)bn * K;

  auto STG = [&](const unsigned short* src, unsigned short* dst, int q, int k0) {
    int rid = q * 32 + w * 8 + (lane >> 3);
    int slot = lane & 7;
    gload_lds16(src + (size_t)rid * K + k0 + ((slot ^ (rid & 7)) << 3),
                dst + (size_t)(q * 2048 + w * 512));
  };
  auto STAGE_ALL = [&](int buf, int k0) {
#pragma unroll
    for (int q = 0; q < BQ; ++q) STG(Bt, lB[buf], q, k0);
#pragma unroll
    for (int q = 0; q < 4; ++q) STG(At, lA[buf], q, k0);
  };

  f32x4 acc[4][NF];
#pragma unroll
  for (int i = 0; i < 4; ++i)
#pragma unroll
    for (int j = 0; j < NF; ++j) acc[i][j] = (f32x4){0.f, 0.f, 0.f, 0.f};

  STAGE_ALL(0, 0);
  asm volatile("s_waitcnt vmcnt(0)" ::: "memory");
  __builtin_amdgcn_s_barrier();

  const int nt = K >> 6;
  for (int t = 0; t < nt; ++t) {
    const int cur = t & 1;
    const char* lAc = (const char*)lA[cur];
    const char* lBc = (const char*)lB[cur];
    const bool more = (t + 1 < nt);
    if (more) STAGE_ALL(cur ^ 1, (t + 1) << 6);

    bfx8 bfrag[NF][2];
#pragma unroll
    for (int nf = 0; nf < NF; ++nf)
#pragma unroll
      for (int kk = 0; kk < 2; ++kk)
        bfrag[nf][kk] = *(const bfx8*)(lBc + (wn + nf * 16 + ln) * 128 +
                                       (((kk * 4 + g) ^ (ln & 7)) << 4));
#pragma unroll
    for (int mf = 0; mf < 4; ++mf) {
      bfx8 afrag[2];
#pragma unroll
      for (int kk = 0; kk < 2; ++kk)
        afrag[kk] = *(const bfx8*)(lAc + (wm + mf * 16 + ln) * 128 +
                                   (((kk * 4 + g) ^ (ln & 7)) << 4));
#pragma unroll
      for (int kk = 0; kk < 2; ++kk)
#pragma unroll
        for (int nf = 0; nf < NF; ++nf)
          acc[mf][nf] = __builtin_amdgcn_mfma_f32_16x16x32_bf16(
              afrag[kk], bfrag[nf][kk], acc[mf][nf], 0, 0, 0);
    }

    asm volatile("s_waitcnt vmcnt(0)" ::: "memory");
    __builtin_amdgcn_s_barrier();
  }

#pragma unroll
  for (int mf = 0; mf < 4; ++mf) {
    int row0 = bm + wm + mf * 16 + g * 4;
#pragma unroll
    for (int nf = 0; nf < NF; ++nf) {
      int col = bn + wn + nf * 16 + ln;
#pragma unroll
      for (int r = 0; r < 4; ++r) {
        if constexpr (BF16OUT)
          ((unsigned short*)Cout)[(size_t)(row0 + r) * N + col] = f2bf(acc[mf][nf][r]);
        else
          ((float*)Cout)[(size_t)(row0 + r) * N + col] = acc[mf][nf][r];
      }
    }
  }
}

// ---------------- Flash attention: 8 waves, q-tile 128, KV chunk 64, LDS-staged ----------------
__global__ __launch_bounds__(512, 4) void flash_kernel(
    const unsigned short* __restrict__ Q, const unsigned short* __restrict__ K,
    const unsigned short* __restrict__ Vt, unsigned short* __restrict__ O) {
  __shared__ unsigned short lKs[2][64 * 128];
  __shared__ unsigned short lVs[2][128 * 64];
  __shared__ unsigned short lP[8][16 * 40];
  const int bh = blockIdx.x;
  const int qy = (int)blockIdx.y;
  const int qt = (qy < 8) ? (15 - qy) : (qy - 8);
  const int q0 = qt * 128;
  const int tid = threadIdx.x;
  const int w = tid >> 6, lane = tid & 63;
  const int g = lane >> 4, ln = lane & 15;
  const int q0w = q0 + w * 16;
  const unsigned short* Qb = Q + (size_t)bh * LSEQ * HD;
  const unsigned short* Kb = K + (size_t)bh * LSEQ * HD;
  const unsigned short* Vb = Vt + (size_t)bh * HD * LSEQ;
  unsigned short* Pw = lP[w];

  auto STAGE = [&](int buf, int kv0s) {
#pragma unroll
    for (int s = 0; s < 2; ++s) {
      int rl = s * 32 + w * 4 + (lane >> 4);
      int slot = lane & 15;
      const unsigned short* src =
          Kb + (size_t)(kv0s + rl) * HD + ((slot ^ (rl & 15)) * 8);
      gload_lds16(src, &lKs[buf][(s * 8192 + w * 1024) / 2]);
    }
#pragma unroll
    for (int s = 0; s < 2; ++s) {
      int d = s * 64 + w * 8 + (lane >> 3);
      int slot = lane & 7;
      const unsigned short* src =
          Vb + (size_t)d * LSEQ + kv0s + ((slot ^ (d & 7)) * 8);
      gload_lds16(src, &lVs[buf][(s * 8192 + w * 1024) / 2]);
    }
  };

  bfx8 qf[4];
#pragma unroll
  for (int c = 0; c < 4; ++c)
    qf[c] = *(const bfx8*)(Qb + (size_t)(q0w + ln) * HD + c * 32 + g * 8);

  f32x4 o[8];
#pragma unroll
  for (int dt = 0; dt < 8; ++dt) o[dt] = (f32x4){0.f, 0.f, 0.f, 0.f};
  float m = -1e30f, sum = 0.f;
  const int qg = q0w + ln;
  const int nch = 2 * qt + 2;

  STAGE(0, 0);
  __syncthreads();

  for (int ch = 0; ch < nch; ++ch) {
    const int kv0 = ch * 64;
    const int cur = ch & 1;
    if (ch + 1 < nch) STAGE(cur ^ 1, kv0 + 64);

    if (kv0 <= q0w + 15) {
      const char* lK0 = (const char*)lKs[cur];
      const char* lV0 = (const char*)lVs[cur];
      f32x4 s4[4];
#pragma unroll
      for (int kt = 0; kt < 4; ++kt) s4[kt] = (f32x4){0.f, 0.f, 0.f, 0.f};
      __builtin_amdgcn_s_setprio(1);
#pragma unroll
      for (int c = 0; c < 4; ++c) {
        const int cbb = c * 64 + g * 16;
#pragma unroll
        for (int kt = 0; kt < 4; ++kt) {
          bfx8 kf = *(const bfx8*)(lK0 + (kt * 16 + ln) * 256 + (cbb ^ (ln << 4)));
          s4[kt] = __builtin_amdgcn_mfma_f32_16x16x32_bf16(kf, qf[c], s4[kt], 0, 0, 0);
        }
      }
      __builtin_amdgcn_s_setprio(0);
      float tm = -1e30f;
      if (kv0 + 63 <= q0w) {
#pragma unroll
        for (int kt = 0; kt < 4; ++kt)
#pragma unroll
          for (int r = 0; r < 4; ++r) {
            s4[kt][r] *= SCALE;
            tm = fmaxf(tm, s4[kt][r]);
          }
      } else {
#pragma unroll
        for (int kt = 0; kt < 4; ++kt)
#pragma unroll
          for (int r = 0; r < 4; ++r) {
            int kvr = kv0 + kt * 16 + 4 * g + r;
            float v = (kvr <= qg) ? s4[kt][r] * SCALE : -1e30f;
            s4[kt][r] = v;
            tm = fmaxf(tm, v);
          }
      }
      tm = fmaxf(tm, __shfl_xor(tm, 16));
      tm = fmaxf(tm, __shfl_xor(tm, 32));
      float f = 1.f;
      const bool dorescale = !__all(tm <= m + 8.f);
      if (dorescale) {
        float mnew = fmaxf(m, tm);
        f = __expf(m - mnew);
        m = mnew;
      }
      float ts = 0.f;
      bfx4 pb4[4];
#pragma unroll
      for (int kt = 0; kt < 4; ++kt)
#pragma unroll
        for (int r = 0; r < 4; ++r) {
          float p = __expf(s4[kt][r] - m);
          ts += p;
          pb4[kt][r] = (short)f2bf(p);
        }
      ts += __shfl_xor(ts, 16);
      ts += __shfl_xor(ts, 32);
      sum = sum * f + ts;
      float fr0 = 1.f, fr1 = 1.f, fr2 = 1.f, fr3 = 1.f;
      if (dorescale) {
        fr0 = __shfl(f, 4 * g + 0);
        fr1 = __shfl(f, 4 * g + 1);
        fr2 = __shfl(f, 4 * g + 2);
        fr3 = __shfl(f, 4 * g + 3);
      }
#pragma unroll
      for (int kvh = 0; kvh < 2; ++kvh) {
        asm volatile("s_waitcnt lgkmcnt(0)" ::: "memory");
        __builtin_amdgcn_sched_barrier(0);
        *(bfx4*)(Pw + ln * 40 + 4 * g) = pb4[2 * kvh];
        *(bfx4*)(Pw + ln * 40 + 16 + 4 * g) = pb4[2 * kvh + 1];
        asm volatile("s_waitcnt lgkmcnt(0)" ::: "memory");
        __builtin_amdgcn_sched_barrier(0);
        bfx8 pf = *(const bfx8*)(Pw + ln * 40 + g * 8);
        if (kvh == 0 && dorescale) {
#pragma unroll
          for (int dt = 0; dt < 8; ++dt) {
            o[dt][0] *= fr0; o[dt][1] *= fr1; o[dt][2] *= fr2; o[dt][3] *= fr3;
          }
        }
        __builtin_amdgcn_s_setprio(1);
#pragma unroll
        for (int dt = 0; dt < 8; ++dt) {
          bfx8 vf = *(const bfx8*)(lV0 + (dt * 16 + ln) * 128 +
                                   ((kvh * 64 + g * 16) ^ ((ln & 7) << 4)));
          o[dt] = __builtin_amdgcn_mfma_f32_16x16x32_bf16(pf, vf, o[dt], 0, 0, 0);
        }
        __builtin_amdgcn_s_setprio(0);
      }
    }
    __syncthreads();
  }

  float inv = 1.f / sum;
  float ir0 = __shfl(inv, 4 * g + 0);
  float ir1 = __shfl(inv, 4 * g + 1);
  float ir2 = __shfl(inv, 4 * g + 2);
  float ir3 = __shfl(inv, 4 * g + 3);
  const int b = bh >> 4, h = bh & 15;
  unsigned short* Ob = O + (size_t)b * LSEQ * HDIM + h * HD;
#pragma unroll
  for (int dt = 0; dt < 8; ++dt) {
    Ob[(size_t)(q0w + 4 * g + 0) * HDIM + dt * 16 + ln] = f2bf(o[dt][0] * ir0);
    Ob[(size_t)(q0w + 4 * g + 1) * HDIM + dt * 16 + ln] = f2bf(o[dt][1] * ir1);
    Ob[(size_t)(q0w + 4 * g + 2) * HDIM + dt * 16 + ln] = f2bf(o[dt][2] * ir2);
    Ob[(size_t)(q0w + 4 * g + 3) * HDIM + dt * 16 + ln] = f2bf(o[dt][3] * ir3);
  }
}

// ---------------- launch ----------------
extern "C" void kernel_launch(void* const* d_in, const int* in_sizes, int n_in,
                              void* d_out, int out_size, void* d_ws, size_t ws_size,
                              hipStream_t stream) {
  const float* x = (const float*)d_in[0];
  const float* w_qkv = (const float*)d_in[1];
  const float* w_o = (const float*)d_in[2];
  float* out = (float*)d_out;
  char* ws = (char*)d_ws;

  unsigned short* xb    = (unsigned short*)(ws + 0);
  unsigned short* wqkvb = (unsigned short*)(ws + 16777216);
  unsigned short* wob   = (unsigned short*)(ws + 41943040);
  unsigned short* qb    = (unsigned short*)(ws + 100663296);
  unsigned short* kb    = (unsigned short*)(ws + 117440512);
  unsigned short* vtb   = (unsigned short*)(ws + 134217728);
  float2* tbl           = (float2*)(ws + 150994944);
  unsigned short* attnb = (unsigned short*)(ws + 0);

  cast_all_kernel<<<24576, 256, 0, stream>>>(x, w_qkv, w_o, xb, wqkvb, wob);
  table_kernel<<<512, 256, 0, stream>>>(tbl);

  // QKV + fused RoPE/scatter: 4-wave blocks, 1024 blocks, 2 blocks/CU
  gemm_qkv_kernel<<<1024, 256, 0, stream>>>(xb, wqkvb, qb, kb, vtb, tbl);

  flash_kernel<<<dim3(32, 16), 512, 0, stream>>>(qb, kb, vtb, attnb);

  gemm4w_kernel<4, false><<<(4096 / 128) * (2048 / 128), 256, 0, stream>>>(
      attnb, wob, (void*)out, 4096, 2048, 2048);
}